// Round 19
// baseline (409.304 us; speedup 1.0000x reference)
//
#include <hip/hip_runtime.h>
#include <math.h>

namespace {
constexpr int cB  = 8;
constexpr int cN  = 4096;
constexpr int cC  = 768;
constexpr int cH  = 12;
constexpr int cHD = 64;
constexpr int cM  = 32;
}

typedef __attribute__((ext_vector_type(8))) short bf16x8;
typedef __attribute__((ext_vector_type(4))) float f32x4;

#define BARRIER() do { asm volatile("" ::: "memory"); __builtin_amdgcn_s_barrier(); asm volatile("" ::: "memory"); } while (0)
#define WAIT_VM(N) do { asm volatile("s_waitcnt vmcnt(" #N ")" ::: "memory"); __builtin_amdgcn_sched_barrier(0); } while (0)
#define WAIT_LGKM0() do { asm volatile("s_waitcnt lgkmcnt(0)" ::: "memory"); __builtin_amdgcn_sched_barrier(0); } while (0)

__device__ __forceinline__ void async_copy16(const void* g, void* l) {
    __builtin_amdgcn_global_load_lds((const __attribute__((address_space(1))) void*)g,
                                     (__attribute__((address_space(3))) void*)l, 16, 0, 0);
}

__device__ __forceinline__ ushort f32_to_bf16_rne(float x) {
    unsigned int u = __float_as_uint(x);
    u += 0x7fffu + ((u >> 16) & 1u);
    return (ushort)(u >> 16);
}

__device__ __forceinline__ float bf16_to_f32(ushort u) {
    return __uint_as_float(((unsigned)u) << 16);
}

// RNE split: f ~= hi + lo, unbiased
__device__ __forceinline__ void split2(float f, ushort& h, ushort& l) {
    h = f32_to_bf16_rne(f);
    float r = f - bf16_to_f32(h);
    l = f32_to_bf16_rne(r);
}

__global__ __launch_bounds__(256)
void split_bf16(const float* __restrict__ in, ushort* __restrict__ hi,
                ushort* __restrict__ lo, int n4)
{
    int i = blockIdx.x * 256 + threadIdx.x;
    const int stride = gridDim.x * 256;
    for (; i < n4; i += stride) {
        float4 v = reinterpret_cast<const float4*>(in)[i];
        ushort4 h, l;
        split2(v.x, h.x, l.x);
        split2(v.y, h.y, l.y);
        split2(v.z, h.z, l.z);
        split2(v.w, h.w, l.w);
        reinterpret_cast<ushort4*>(hi)[i] = h;
        reinterpret_cast<ushort4*>(lo)[i] = l;
    }
}

// 128x256-tile GEMM (round-19: BM halved for 2 blocks/CU), 16x16x32 MFMA,
// BK=32, double-buffered LDS, per-phase interleave + counted boundary vmcnt.
// TERMS=2: (Ah+Al)xBh;  TERMS=1: AhxBh.  8 waves = 2M x 4N, wave = 64x64
// (one head) -> FUSE invariant kept.
// FUSE=0 epilogue: mode 0 fp32 [M,Ndim]; mode 2 bf16 v-permuted [b,h,t,d].
// FUSE=1 (kq): per wave run the Performer feature map in 2 passes of 32 rows
// (8KB/wave scratch aliasing smem, 64KB total = exactly the dbuf footprint);
// kp/qp row-major [bh][t][m] + kpsum partials (wave = one 64-row tblk).
// vmcnt ledger: prologue issues tiles 0,1 (APL+2 loads each) -> WAIT(APL+2);
// steady: ph0/1 issue A(t+1) (APL), ph2/3 issue B(t+2) (2); boundary WAIT(2)
// leaves only B(t+2) in flight; tail WAIT(0).
template <int TERMS, int FUSE>
__global__ __launch_bounds__(512, 4)
void gemm256(const ushort* __restrict__ Ah, const ushort* __restrict__ Al,
             const ushort* __restrict__ Bh,
             const float* __restrict__ bias,
             float* __restrict__ Cf, ushort* __restrict__ Cb,
             int Ndim, int K, int mode,
             ushort* __restrict__ kp, ushort* __restrict__ qp,
             float* __restrict__ kpsum_p,
             const ushort* __restrict__ whb, const ushort* __restrict__ wlb)
{
    constexpr int APL = (TERMS >= 2) ? 2 : 1;     // A planes
    constexpr int ASZ = 4096;                     // [128][32] ushorts
    constexpr int BSZ = 8192;                     // [256][32] ushorts
    constexpr int BUF = APL * ASZ + BSZ;          // per-dbuf stride (ushorts)
    constexpr int SMEMSZ = (2 * BUF > (FUSE ? 32768 : 0)) ? 2 * BUF : 32768;
    __shared__ ushort smem[SMEMSZ];
    const int tid = threadIdx.x;
    const int wave = tid >> 6, lane = tid & 63;
    const int wm = wave >> 2, wn = wave & 3;      // 2M x 4N waves, 64x64 each
    const int fr = lane & 15, fk = lane >> 4;
    const int fco = (fk ^ ((fr >> 1) & 3)) * 8;   // measured-0-conflict chunk

    // XCD-chunked swizzle, col-major ids (nwg % 8 == 0 for all grids used)
    const int NY = gridDim.y;
    const int nwg = gridDim.x * NY;
    const int orig = blockIdx.x * NY + blockIdx.y;
    const int swz = (orig & 7) * (nwg >> 3) + (orig >> 3);
    const int row0 = (swz % NY) << 7;             // 128-row tiles
    const int col0 = (swz / NY) << 8;             // 256-col tiles

    const ushort* aplanes[APL];
    aplanes[0] = Ah;
    if constexpr (APL == 2) aplanes[1] = Al;

    // staging descriptors: linear LDS dest + inverse source-side chunk swizzle
    // A: 512 chunks/plane, 1 per thread;  B: 1024 chunks, 2 per thread.
    const ushort* gsrcA[APL];
    int ldstA[APL];
    #pragma unroll
    for (int p = 0; p < APL; ++p) {
        const int row = tid >> 2;
        const int cc = (tid & 3) ^ ((row >> 1) & 3);
        gsrcA[p] = aplanes[p] + (size_t)(row0 + row) * K + cc * 8;
        ldstA[p] = p * ASZ + tid * 8;
    }
    const ushort* gsrcB[2];
    int ldstB[2];
    #pragma unroll
    for (int h2 = 0; h2 < 2; ++h2) {
        const int ci = h2 * 512 + tid;
        const int row = ci >> 2;
        const int cc = (ci & 3) ^ ((row >> 1) & 3);
        gsrcB[h2] = Bh + (size_t)(col0 + row) * K + cc * 8;
        ldstB[h2] = APL * ASZ + h2 * 4096 + tid * 8;
    }

    const int NT = K >> 5;
    f32x4 acc[4][4] = {};

    // prologue: tile0 -> buf0, tile1 -> buf1; wait tile0 (tile1 stays in flight)
    #pragma unroll
    for (int p = 0; p < APL; ++p) async_copy16(gsrcA[p], &smem[ldstA[p]]);
    #pragma unroll
    for (int h2 = 0; h2 < 2; ++h2) async_copy16(gsrcB[h2], &smem[ldstB[h2]]);
    #pragma unroll
    for (int p = 0; p < APL; ++p) async_copy16(gsrcA[p] + 32, &smem[BUF + ldstA[p]]);
    #pragma unroll
    for (int h2 = 0; h2 < 2; ++h2) async_copy16(gsrcB[h2] + 32, &smem[BUF + ldstB[h2]]);
    if constexpr (TERMS == 2) WAIT_VM(4); else WAIT_VM(3);
    BARRIER();

    for (int t = 0; t < NT; ++t) {
        const int cb = (t & 1) * BUF;
        const int nb = ((t + 1) & 1) * BUF;
        bf16x8 fb[4];
        #pragma unroll
        for (int mp = 0; mp < 4; ++mp) {
            // --- phase ds-reads ---
            if (mp == 0) {
                #pragma unroll
                for (int ni = 0; ni < 4; ++ni) {
                    const int off = cb + APL * ASZ + (wn * 64 + ni * 16 + fr) * 32 + fco;
                    fb[ni] = *reinterpret_cast<const bf16x8*>(&smem[off]);
                }
            }
            bf16x8 fa[APL];
            {
                const int off = cb + (wm * 64 + mp * 16 + fr) * 32 + fco;
                fa[0] = *reinterpret_cast<const bf16x8*>(&smem[off]);
                if constexpr (APL == 2)
                    fa[1] = *reinterpret_cast<const bf16x8*>(&smem[off + ASZ]);
            }
            // --- phase prefetch issues: ph0/1 A(t+1), ph2/3 B(t+2) ---
            if (t >= 1 && t + 1 < NT && mp < APL)
                async_copy16(gsrcA[mp] + (t + 1) * 32, &smem[nb + ldstA[mp]]);
            if (t + 2 < NT && mp >= 2)
                async_copy16(gsrcB[mp - 2] + (t + 2) * 32, &smem[cb + ldstB[mp - 2]]);
            // --- barrier / wait / MFMA cluster ---
            BARRIER();
            WAIT_LGKM0();
            __builtin_amdgcn_s_setprio(1);
            #pragma unroll
            for (int term = 0; term < TERMS; ++term)
                #pragma unroll
                for (int ni = 0; ni < 4; ++ni)
                    acc[mp][ni] = __builtin_amdgcn_mfma_f32_16x16x32_bf16(
                        fa[term], fb[ni], acc[mp][ni], 0, 0, 0);
            __builtin_amdgcn_s_setprio(0);
            // --- boundary counted wait (only at last phase) ---
            if (mp == 3) {
                if (t + 2 < NT)      WAIT_VM(2);
                else if (t + 1 < NT) WAIT_VM(0);
            }
            if (mp < 3 || t + 1 < NT) BARRIER();
        }
    }

    if constexpr (FUSE) {
        // ---- fused Performer feature map (wave = one head, 64 rows) ----
        BARRIER();   // all waves done with main-loop smem reads
        const int cglob = col0 + wn * 64;
        const bool is_k = (cglob < 768);
        const int h = (is_k ? cglob : cglob - 768) >> 6;
        const int rbase = row0 + wm * 64;
        const int b = rbase >> 12;
        const int bh = b * cH + h;
        const int trow0 = rbase & 4095;
        ushort* phi = is_k ? kp : qp;
        bf16x8 Wh2[2][2], Wl2[2][2];
        #pragma unroll
        for (int mf = 0; mf < 2; ++mf)
            #pragma unroll
            for (int kc = 0; kc < 2; ++kc) {
                size_t off = (size_t)(h * 32 + mf * 16 + fr) * 64 + kc * 32 + fk * 8;
                Wh2[mf][kc] = *reinterpret_cast<const bf16x8*>(&whb[off]);
                Wl2[mf][kc] = *reinterpret_cast<const bf16x8*>(&wlb[off]);
            }
        unsigned* kt = reinterpret_cast<unsigned*>(&smem[wave * 4096]); // [32][64] u32, 8KB/wave
        const float rsm = 0.17677669529663687f;  // 1/sqrt(32)
        float sm0 = 0.f, sm1 = 0.f;
        #pragma unroll
        for (int pass = 0; pass < 2; ++pass) {
            // stage 32 rows: packed (lo<<16|hi), XOR chunk swizzle cc^(row&15)
            #pragma unroll
            for (int ni = 0; ni < 4; ++ni) {
                const float bv = bias[cglob + ni * 16 + fr];
                #pragma unroll
                for (int mi2 = 0; mi2 < 2; ++mi2) {
                    #pragma unroll
                    for (int j = 0; j < 4; ++j) {
                        const int rrow = mi2 * 16 + fk * 4 + j;   // 0..31
                        const int ccol = ni * 16 + fr;            // 0..63
                        ushort hh, ll;
                        split2(acc[pass * 2 + mi2][ni][j] + bv, hh, ll);
                        const int ccs = (ccol >> 2) ^ (rrow & 15);
                        kt[rrow * 64 + ccs * 4 + (ccol & 3)] = ((unsigned)ll << 16) | hh;
                    }
                }
            }
            f32x4 acc2[2][2] = {};
            float xdv4[2];
            #pragma unroll
            for (int tf = 0; tf < 2; ++tf) {
                const int rrow = tf * 16 + fr;
                const unsigned* rowp = &kt[rrow * 64];
                uint4 c0 = *reinterpret_cast<const uint4*>(&rowp[(((fk << 1))     ^ fr) << 2]);
                uint4 c1 = *reinterpret_cast<const uint4*>(&rowp[(((fk << 1) | 1) ^ fr) << 2]);
                uint4 c2 = *reinterpret_cast<const uint4*>(&rowp[(((fk << 1) + 8) ^ fr) << 2]);
                uint4 c3 = *reinterpret_cast<const uint4*>(&rowp[(((fk << 1) + 9) ^ fr) << 2]);
                unsigned u[16] = {c0.x,c0.y,c0.z,c0.w, c1.x,c1.y,c1.z,c1.w,
                                  c2.x,c2.y,c2.z,c2.w, c3.x,c3.y,c3.z,c3.w};
                bf16x8 Ah2[2], Al2[2];
                float xs = 0.f;
                #pragma unroll
                for (int e = 0; e < 16; ++e) {
                    const ushort hh = (ushort)(u[e] & 0xffffu);
                    const ushort ll = (ushort)(u[e] >> 16);
                    Ah2[e >> 3][e & 7] = (short)hh;
                    Al2[e >> 3][e & 7] = (short)ll;
                    const float kv = bf16_to_f32(hh) + bf16_to_f32(ll);
                    xs = fmaf(kv, kv, xs);
                }
                xs += __shfl_xor(xs, 16);
                xs += __shfl_xor(xs, 32);
                xdv4[tf] = 0.5f * xs;
                #pragma unroll
                for (int kc = 0; kc < 2; ++kc)
                    #pragma unroll
                    for (int mf = 0; mf < 2; ++mf) {
                        acc2[tf][mf] = __builtin_amdgcn_mfma_f32_16x16x32_bf16(Ah2[kc], Wh2[mf][kc], acc2[tf][mf], 0, 0, 0);
                        acc2[tf][mf] = __builtin_amdgcn_mfma_f32_16x16x32_bf16(Ah2[kc], Wl2[mf][kc], acc2[tf][mf], 0, 0, 0);
                        acc2[tf][mf] = __builtin_amdgcn_mfma_f32_16x16x32_bf16(Al2[kc], Wh2[mf][kc], acc2[tf][mf], 0, 0, 0);
                    }
            }
            #pragma unroll
            for (int tf = 0; tf < 2; ++tf) {
                #pragma unroll
                for (int j = 0; j < 4; ++j) {
                    const int rloc = fk * 4 + j;
                    const float xdv = __shfl(xdv4[tf], (lane & 48) | rloc);
                    const int tg = trow0 + pass * 32 + tf * 16 + rloc;
                    float e0 = __expf(acc2[tf][0][j] - xdv) * rsm;
                    float e1 = __expf(acc2[tf][1][j] - xdv) * rsm;
                    phi[((size_t)bh * cN + tg) * cM + fr]      = f32_to_bf16_rne(e0);
                    phi[((size_t)bh * cN + tg) * cM + 16 + fr] = f32_to_bf16_rne(e1);
                    sm0 += e0; sm1 += e1;
                }
            }
        }
        if (is_k) {
            sm0 += __shfl_xor(sm0, 16); sm0 += __shfl_xor(sm0, 32);
            sm1 += __shfl_xor(sm1, 16); sm1 += __shfl_xor(sm1, 32);
            const int tblk = trow0 >> 6;
            if (lane < 16) {
                kpsum_p[((size_t)bh * 64 + tblk) * cM + lane]      = sm0;
                kpsum_p[((size_t)bh * 64 + tblk) * cM + 16 + lane] = sm1;
            }
        }
        return;
    }

    // FUSE=0 epilogue: 16x16 C layout col=lane&15, row=(lane>>4)*4+j
    #pragma unroll
    for (int ni = 0; ni < 4; ++ni) {
        const int c = col0 + wn * 64 + ni * 16 + fr;
        const float bv = bias[c];
        #pragma unroll
        for (int mi = 0; mi < 4; ++mi) {
            const int r0 = row0 + wm * 64 + mi * 16 + fk * 4;
            #pragma unroll
            for (int j = 0; j < 4; ++j) {
                const float val = acc[mi][ni][j] + bv;
                const int row = r0 + j;
                if (mode == 0) {
                    Cf[(size_t)row * Ndim + c] = val;
                } else {
                    const int b = row >> 12, tt = row & 4095;
                    const int h = c >> 6, d = c & 63;
                    Cb[(((size_t)(b * cH + h) * cN + tt) << 6) + d] = f32_to_bf16_rne(val);
                }
            }
        }
    }
}

// y = (qp . kptv) / (qp . kpsum + eps) via one MFMA pass (D appended as B-row 64)
// 4 waves/block; writes yh only (proj is TERMS=1)
__global__ __launch_bounds__(256)
void pv_mfma(const ushort* __restrict__ qp, const ushort* __restrict__ kptvx,
             ushort* __restrict__ yh)
{
    const int bh = blockIdx.x;
    const int wave = threadIdx.x >> 6, lane = threadIdx.x & 63;
    const int tblk = blockIdx.y * 4 + wave;
    const int b = bh / cH, h = bh % cH;
    const int t0 = tblk * 64;
    const int fr = lane & 15, fk = lane >> 4;
    bf16x8 Bf[5];
    #pragma unroll
    for (int nf = 0; nf < 5; ++nf)
        Bf[nf] = *reinterpret_cast<const bf16x8*>(&kptvx[(size_t)bh * 2560 + (nf * 16 + fr) * 32 + fk * 8]);
    f32x4 acc[4][5] = {};
    #pragma unroll
    for (int tf = 0; tf < 4; ++tf) {
        bf16x8 Af = *reinterpret_cast<const bf16x8*>(&qp[((size_t)bh * cN + t0 + tf * 16 + fr) * cM + fk * 8]);
        #pragma unroll
        for (int nf = 0; nf < 5; ++nf)
            acc[tf][nf] = __builtin_amdgcn_mfma_f32_16x16x32_bf16(Af, Bf[nf], acc[tf][nf], 0, 0, 0);
    }
    #pragma unroll
    for (int tf = 0; tf < 4; ++tf) {
        #pragma unroll
        for (int j = 0; j < 4; ++j) {
            const int rloc = fk * 4 + j;
            const int t = t0 + tf * 16 + rloc;
            const float Dv = __shfl(acc[tf][4][j], lane & 48) + 1e-8f;
            const float rD = 1.0f / Dv;
            #pragma unroll
            for (int nf = 0; nf < 4; ++nf) {
                float yv = acc[tf][nf][j] * rD;
                size_t oa = (size_t)(b * cN + t) * cC + h * 64 + nf * 16 + fr;
                yh[oa] = f32_to_bf16_rne(yv);
            }
        }
    }
}

// kptv partials: kptv_p[c][bh][d][m] over 32-t slices; c = chunk*2+half, 16 total
__global__ __launch_bounds__(256, 4)
void kptv_part(const ushort* __restrict__ vbf, const ushort* __restrict__ kp,
               float* __restrict__ kptv_p)
{
    const int bh = blockIdx.x, chunk = blockIdx.y;
    __shared__ float vl[64][68];
    __shared__ float kl[64][36];
    const int tid = threadIdx.x;
    const int half = tid >> 7;
    const int dg = (tid >> 3) & 15;
    const int mg = tid & 7;
    float acc[4][4] = {};
    for (int tile = 0; tile < 8; ++tile) {
        const int tb = chunk * 512 + tile * 64;
        #pragma unroll
        for (int i = 0; i < 2; ++i) {
            int idx = i * 256 + tid;
            int row = idx >> 3, seg = idx & 7;
            bf16x8 vv = *reinterpret_cast<const bf16x8*>(&vbf[((size_t)bh * cN + tb + row) * 64 + seg * 8]);
            float4 lo4 = make_float4(bf16_to_f32((ushort)vv[0]), bf16_to_f32((ushort)vv[1]),
                                     bf16_to_f32((ushort)vv[2]), bf16_to_f32((ushort)vv[3]));
            float4 hi4 = make_float4(bf16_to_f32((ushort)vv[4]), bf16_to_f32((ushort)vv[5]),
                                     bf16_to_f32((ushort)vv[6]), bf16_to_f32((ushort)vv[7]));
            *reinterpret_cast<float4*>(&vl[row][seg * 8])     = lo4;
            *reinterpret_cast<float4*>(&vl[row][seg * 8 + 4]) = hi4;
        }
        {
            int row = tid >> 2, seg = tid & 3;
            bf16x8 vv = *reinterpret_cast<const bf16x8*>(&kp[((size_t)bh * cN + tb + row) * 32 + seg * 8]);
            float4 lo4 = make_float4(bf16_to_f32((ushort)vv[0]), bf16_to_f32((ushort)vv[1]),
                                     bf16_to_f32((ushort)vv[2]), bf16_to_f32((ushort)vv[3]));
            float4 hi4 = make_float4(bf16_to_f32((ushort)vv[4]), bf16_to_f32((ushort)vv[5]),
                                     bf16_to_f32((ushort)vv[6]), bf16_to_f32((ushort)vv[7]));
            *reinterpret_cast<float4*>(&kl[row][seg * 8])     = lo4;
            *reinterpret_cast<float4*>(&kl[row][seg * 8 + 4]) = hi4;
        }
        __syncthreads();
        for (int t = 0; t < 32; ++t) {
            const int tt = half * 32 + t;
            float4 av = *reinterpret_cast<const float4*>(&vl[tt][dg * 4]);
            float4 bv = *reinterpret_cast<const float4*>(&kl[tt][mg * 4]);
            float a4[4] = {av.x, av.y, av.z, av.w};
            float b4[4] = {bv.x, bv.y, bv.z, bv.w};
            #pragma unroll
            for (int i = 0; i < 4; ++i)
                #pragma unroll
                for (int j = 0; j < 4; ++j)
                    acc[i][j] = fmaf(a4[i], b4[j], acc[i][j]);
        }
        __syncthreads();
    }
    float* outp = &kptv_p[(((size_t)chunk * 2 + half) * 96 + bh) * 2048];
    #pragma unroll
    for (int i = 0; i < 4; ++i)
        *reinterpret_cast<float4*>(&outp[(dg * 4 + i) * 32 + mg * 4]) =
            make_float4(acc[i][0], acc[i][1], acc[i][2], acc[i][3]);
}

// reduce partials -> kptvx bf16 [bh][80][32]: rows 0..63 kptv, row 64 kpsum, 65..79 zero
__global__ __launch_bounds__(256)
void kptv_reduce(const float* __restrict__ kptv_p, const float* __restrict__ kpsum_p,
                 ushort* __restrict__ kptvx)
{
    const int bh = blockIdx.x, tid = threadIdx.x;
    for (int l = tid; l < 2048; l += 256) {
        float s = 0.f;
        #pragma unroll
        for (int c = 0; c < 16; ++c) s += kptv_p[((size_t)c * 96 + bh) * 2048 + l];
        kptvx[(size_t)bh * 2560 + l] = f32_to_bf16_rne(s);
    }
    if (tid < 32) {
        float s = 0.f;
        #pragma unroll
        for (int c = 0; c < 64; ++c) s += kpsum_p[((size_t)bh * 64 + c) * cM + tid];
        kptvx[(size_t)bh * 2560 + 64 * 32 + tid] = f32_to_bf16_rne(s);
    }
    for (int l = tid; l < 480; l += 256)
        kptvx[(size_t)bh * 2560 + 65 * 32 + l] = 0;
}

extern "C" void kernel_launch(void* const* d_in, const int* in_sizes, int n_in,
                              void* d_out, int out_size, void* d_ws, size_t ws_size,
                              hipStream_t stream)
{
    const float* x      = (const float*)d_in[0];
    const float* kqv_w  = (const float*)d_in[1];
    const float* kqv_b  = (const float*)d_in[2];
    const float* proj_w = (const float*)d_in[3];
    const float* proj_b = (const float*)d_in[4];
    const float* w      = (const float*)d_in[5];

    char* wsb = (char*)d_ws;
    ushort* xh   = (ushort*)(wsb);                 // x hi plane, 50,331,648 B
    ushort* xl   = (ushort*)(wsb + 50331648);      // x lo plane
    ushort* yh   = (ushort*)(wsb + 100663296);     // y hi plane (written by pv)
    ushort* vbf  = (ushort*)(wsb + 201326592);     // [96][4096][64] bf16
    ushort* wh   = (ushort*)(wsb + 251658240);     // kqv_w hi
    ushort* wl_  = (ushort*)(wsb + 255197184);     // kqv_w lo
    ushort* pwh  = (ushort*)(wsb + 258736128);     // proj_w hi
    ushort* pwl  = (ushort*)(wsb + 259915776);     // proj_w lo (layout keep)
    ushort* whb  = (ushort*)(wsb + 261095424);     // w hi (bf16)
    ushort* wlb  = (ushort*)(wsb + 261144576);     // w lo

    char* ob = (char*)d_out;
    ushort* kp      = (ushort*)ob;                 // [96][4096][32] bf16
    ushort* qp      = (ushort*)(ob + 25165824);    // [96][4096][32] bf16
    float*  kptv_p  = (float*)(ob + 50331648);     // [16][96][2048] fp32
    float*  kpsum_p = (float*)(ob + 62914560);     // [96][64][32] fp32
    ushort* kptvx   = (ushort*)(ob + 63700992);    // [96][80][32] bf16
    float*  out     = (float*)d_out;

    dim3 blk(256);
    // splits (RNE hi/lo planes)
    split_bf16<<<2048, blk, 0, stream>>>(x, xh, xl, 25165824 / 4);
    split_bf16<<<1728, blk, 0, stream>>>(kqv_w, wh, wl_, 1769472 / 4);
    split_bf16<<<576, blk, 0, stream>>>(proj_w, pwh, pwl, 589824 / 4);
    split_bf16<<<24, blk, 0, stream>>>(w, whb, wlb, 24576 / 4);
    // fused kq GEMM + feature map, TERMS=2 (128x256 tiles, 2 blocks/CU)
    gemm256<2, 1><<<dim3(6, 256), dim3(512), 0, stream>>>(
        xh, xl, wh, kqv_b, nullptr, nullptr, 1536, 768, 0,
        kp, qp, kpsum_p, whb, wlb);
    // v = x @ kqv_w[1536:2304]^T  (bf16 out, 1-term, [b,h,t,d] layout)
    gemm256<1, 0><<<dim3(3, 256), dim3(512), 0, stream>>>(
        xh, nullptr, wh + (size_t)1536 * 768, kqv_b + 1536,
        nullptr, vbf, 768, 768, 2, nullptr, nullptr, nullptr, nullptr, nullptr);
    // kptv partials + reduce
    kptv_part<<<dim3(96, 8), blk, 0, stream>>>(vbf, kp, kptv_p);
    kptv_reduce<<<dim3(96), blk, 0, stream>>>(kptv_p, kpsum_p, kptvx);
    // normalized PV -> yh (4 waves/block)
    pv_mfma<<<dim3(96, 16), blk, 0, stream>>>(qp, kptvx, yh);
    // out = y @ proj_w^T + proj_b  (1-term yh*pwh)
    gemm256<1, 0><<<dim3(3, 256), dim3(512), 0, stream>>>(
        yh, nullptr, pwh, proj_b, out, nullptr, 768, 768, 0,
        nullptr, nullptr, nullptr, nullptr, nullptr);
}

// Round 20
// 389.644 us; speedup vs baseline: 1.0505x; 1.0505x over previous
//
#include <hip/hip_runtime.h>
#include <math.h>

namespace {
constexpr int cB  = 8;
constexpr int cN  = 4096;
constexpr int cC  = 768;
constexpr int cH  = 12;
constexpr int cHD = 64;
constexpr int cM  = 32;
}

typedef __attribute__((ext_vector_type(8))) short bf16x8;
typedef __attribute__((ext_vector_type(4))) float f32x4;

#define BARRIER() do { asm volatile("" ::: "memory"); __builtin_amdgcn_s_barrier(); asm volatile("" ::: "memory"); } while (0)
#define WAIT_VM(N) do { asm volatile("s_waitcnt vmcnt(" #N ")" ::: "memory"); __builtin_amdgcn_sched_barrier(0); } while (0)
#define WAIT_LGKM0() do { asm volatile("s_waitcnt lgkmcnt(0)" ::: "memory"); __builtin_amdgcn_sched_barrier(0); } while (0)

__device__ __forceinline__ void async_copy16(const void* g, void* l) {
    __builtin_amdgcn_global_load_lds((const __attribute__((address_space(1))) void*)g,
                                     (__attribute__((address_space(3))) void*)l, 16, 0, 0);
}

__device__ __forceinline__ ushort f32_to_bf16_rne(float x) {
    unsigned int u = __float_as_uint(x);
    u += 0x7fffu + ((u >> 16) & 1u);
    return (ushort)(u >> 16);
}

__device__ __forceinline__ float bf16_to_f32(ushort u) {
    return __uint_as_float(((unsigned)u) << 16);
}

// RNE split: f ~= hi + lo, unbiased
__device__ __forceinline__ void split2(float f, ushort& h, ushort& l) {
    h = f32_to_bf16_rne(f);
    float r = f - bf16_to_f32(h);
    l = f32_to_bf16_rne(r);
}

__global__ __launch_bounds__(256)
void split_bf16(const float* __restrict__ in, ushort* __restrict__ hi,
                ushort* __restrict__ lo, int n4)
{
    int i = blockIdx.x * 256 + threadIdx.x;
    const int stride = gridDim.x * 256;
    for (; i < n4; i += stride) {
        float4 v = reinterpret_cast<const float4*>(in)[i];
        ushort4 h, l;
        split2(v.x, h.x, l.x);
        split2(v.y, h.y, l.y);
        split2(v.z, h.z, l.z);
        split2(v.w, h.w, l.w);
        reinterpret_cast<ushort4*>(hi)[i] = h;
        reinterpret_cast<ushort4*>(lo)[i] = l;
    }
}

// 256x256-tile GEMM, 16x16x32 MFMA, BK=32, double-buffered LDS, per-phase
// interleave + counted boundary vmcnt (round-11 schedule, PASSING).
// TERMS=3: (Ah+Al)x(Bh+Bl) 3-product;  TERMS=2: (Ah+Al)xBh;  TERMS=1: AhxBh.
// FUSE=0 epilogue: mode 0 fp32 [M,Ndim]; mode 2 bf16 v-permuted [b,h,t,d]
// (coalesced runs -- round-16 lesson: transposed global stores de-coalesce).
// FUSE=1 (kq only): per wave (= one head's 64 cols) run the Performer feature
// map from LDS-staged rows; kp/qp row-major [bh][t][m] + kpsum partials.
// FUSE scratch needs 8 waves x 16KB = 128KB -> smem padded to 65536 ushorts.
// Round-19/16 lessons: BM=128 halves arithmetic intensity (FETCH 84->194MB,
// regressed); transposed outputs de-coalesce producers. 256x256 TERMS=2 at
// ~178us is this decomposition's floor.
template <int TERMS, int FUSE>
__global__ __launch_bounds__(512, 2)
void gemm256(const ushort* __restrict__ Ah, const ushort* __restrict__ Al,
             const ushort* __restrict__ Bh, const ushort* __restrict__ Bl,
             const float* __restrict__ bias,
             float* __restrict__ Cf, ushort* __restrict__ Cb,
             int Ndim, int K, int mode,
             ushort* __restrict__ kp, ushort* __restrict__ qp,
             float* __restrict__ kpsum_p,
             const ushort* __restrict__ whb, const ushort* __restrict__ wlb)
{
    constexpr int APL = (TERMS >= 2) ? 2 : 1;   // A planes
    constexpr int BPL = (TERMS == 3) ? 2 : 1;   // B planes
    constexpr int NPL = APL + BPL;
    constexpr int SMEMSZ = (FUSE && 2 * NPL * 8192 < 65536) ? 65536 : 2 * NPL * 8192;
    __shared__ ushort smem[SMEMSZ];             // 2 bufs x NPL x [256][32] (+FUSE pad)
    const int tid = threadIdx.x;
    const int wave = tid >> 6, lane = tid & 63;
    const int wm = wave >> 2, wn = wave & 3;    // 2M x 4N waves, 128x64 each
    const int fr = lane & 15, fk = lane >> 4;
    const int fco = (fk ^ ((fr >> 1) & 3)) * 8; // round-5 measured-0-conflict chunk

    // XCD-chunked swizzle (gridDim.y == 128; nwg % 8 == 0)
    const int nwg = gridDim.x * 128;
    const int orig = blockIdx.x * 128 + blockIdx.y;
    const int swz = (orig & 7) * (nwg >> 3) + (orig >> 3);
    const int row0 = (swz & 127) << 8;
    const int col0 = (swz >> 7) << 8;

    const ushort* planes[NPL];
    if constexpr (TERMS == 3) { planes[0] = Ah; planes[1] = Al; planes[2] = Bh; planes[3] = Bl; }
    else if constexpr (TERMS == 2) { planes[0] = Ah; planes[1] = Al; planes[2] = Bh; }
    else { planes[0] = Ah; planes[1] = Bh; }

    // staging: linear LDS dest + inverse source-side chunk swizzle (rule #21)
    const ushort* gsrc[NPL][2];
    int ldst[NPL][2];
    #pragma unroll
    for (int p = 0; p < NPL; ++p)
        #pragma unroll
        for (int h2 = 0; h2 < 2; ++h2) {
            const int ci = h2 * 512 + tid;
            const int row = ci >> 2;
            const int cc = (ci & 3) ^ ((row >> 1) & 3);
            const int grow = ((p < APL) ? row0 : col0) + row;
            gsrc[p][h2] = planes[p] + (size_t)grow * K + cc * 8;
            ldst[p][h2] = p * 8192 + h2 * 4096 + wave * 512;   // wave-uniform base
        }

    const int NT = K >> 5;
    f32x4 acc[8][4] = {};

    // prologue: tile0 -> buf0, tile1 -> buf1; wait tile0 (tile1 stays in flight)
    #pragma unroll
    for (int p = 0; p < NPL; ++p)
        #pragma unroll
        for (int h2 = 0; h2 < 2; ++h2)
            async_copy16(gsrc[p][h2], &smem[ldst[p][h2]]);
    #pragma unroll
    for (int p = 0; p < NPL; ++p)
        #pragma unroll
        for (int h2 = 0; h2 < 2; ++h2)
            async_copy16(gsrc[p][h2] + 32, &smem[NPL * 8192 + ldst[p][h2]]);
    if constexpr (TERMS == 3) WAIT_VM(8);
    else if constexpr (TERMS == 2) WAIT_VM(6);
    else WAIT_VM(4);
    BARRIER();

    for (int t = 0; t < NT; ++t) {
        const int cb = (t & 1) * NPL * 8192;
        const int nb = ((t + 1) & 1) * NPL * 8192;
        bf16x8 fb[4][BPL];
        #pragma unroll
        for (int mp = 0; mp < 4; ++mp) {
            if (mp == 0) {
                #pragma unroll
                for (int ni = 0; ni < 4; ++ni) {
                    const int off = cb + APL * 8192 + (wn * 64 + ni * 16 + fr) * 32 + fco;
                    fb[ni][0] = *reinterpret_cast<const bf16x8*>(&smem[off]);
                    if constexpr (BPL == 2)
                        fb[ni][1] = *reinterpret_cast<const bf16x8*>(&smem[off + 8192]);
                }
            }
            bf16x8 fa[2][APL];
            #pragma unroll
            for (int m2 = 0; m2 < 2; ++m2) {
                const int off = cb + (wm * 128 + (mp * 2 + m2) * 16 + fr) * 32 + fco;
                fa[m2][0] = *reinterpret_cast<const bf16x8*>(&smem[off]);
                if constexpr (APL == 2)
                    fa[m2][1] = *reinterpret_cast<const bf16x8*>(&smem[off + 8192]);
            }
            if (t >= 1 && t + 1 < NT && mp < APL) {
                async_copy16(gsrc[mp][0] + (t + 1) * 32, &smem[nb + ldst[mp][0]]);
                async_copy16(gsrc[mp][1] + (t + 1) * 32, &smem[nb + ldst[mp][1]]);
            }
            if (t + 2 < NT && mp >= APL && mp < APL + BPL) {
                async_copy16(gsrc[mp][0] + (t + 2) * 32, &smem[cb + ldst[mp][0]]);
                async_copy16(gsrc[mp][1] + (t + 2) * 32, &smem[cb + ldst[mp][1]]);
            }
            BARRIER();
            WAIT_LGKM0();
            __builtin_amdgcn_s_setprio(1);
            #pragma unroll
            for (int term = 0; term < TERMS; ++term) {
                const int pa = (TERMS == 3) ? ((term == 2) ? 1 : 0)
                             : (TERMS == 2) ? term : 0;
                const int pb = (TERMS == 3) ? ((term == 1) ? 1 : 0) : 0;
                #pragma unroll
                for (int m2 = 0; m2 < 2; ++m2)
                    #pragma unroll
                    for (int ni = 0; ni < 4; ++ni)
                        acc[mp * 2 + m2][ni] = __builtin_amdgcn_mfma_f32_16x16x32_bf16(
                            fa[m2][pa], fb[ni][pb], acc[mp * 2 + m2][ni], 0, 0, 0);
            }
            __builtin_amdgcn_s_setprio(0);
            if (mp == 3) {
                if (t + 2 < NT)      { if constexpr (BPL == 2) WAIT_VM(4); else WAIT_VM(2); }
                else if (t + 1 < NT) { WAIT_VM(0); }
            }
            if (mp < 3 || t + 1 < NT) BARRIER();
        }
    }

    if constexpr (FUSE) {
        // ---- fused Performer feature map (per wave = one head slice) ----
        BARRIER();   // all waves done with main-loop smem reads
        const int cglob = col0 + wn * 64;
        const bool is_k = (cglob < 768);
        const int h = (is_k ? cglob : cglob - 768) >> 6;
        const int rbase = row0 + wm * 128;       // 256-row block lies in one b
        const int b = rbase >> 12;
        const int bh = b * cH + h;
        const int trow0 = rbase & 4095;
        ushort* phi = is_k ? kp : qp;
        // w fragments for this head (same layout as the old prm_exp_mfma)
        bf16x8 Wh2[2][2], Wl2[2][2];
        #pragma unroll
        for (int mf = 0; mf < 2; ++mf)
            #pragma unroll
            for (int kc = 0; kc < 2; ++kc) {
                size_t off = (size_t)(h * 32 + mf * 16 + fr) * 64 + kc * 32 + fk * 8;
                Wh2[mf][kc] = *reinterpret_cast<const bf16x8*>(&whb[off]);
                Wl2[mf][kc] = *reinterpret_cast<const bf16x8*>(&wlb[off]);
            }
        unsigned* kt = reinterpret_cast<unsigned*>(&smem[wave * 8192]); // [64][64] u32, 16KB/wave
        const float rsm = 0.17677669529663687f;  // 1/sqrt(32)
        #pragma unroll
        for (int pass = 0; pass < 2; ++pass) {
            // stage 64 rows: packed (lo<<16|hi) with XOR chunk swizzle cc^(row&15)
            #pragma unroll
            for (int ni = 0; ni < 4; ++ni) {
                const float bv = bias[cglob + ni * 16 + fr];
                #pragma unroll
                for (int mi = 0; mi < 4; ++mi) {
                    #pragma unroll
                    for (int j = 0; j < 4; ++j) {
                        const int rrow = mi * 16 + fk * 4 + j;   // 0..63
                        const int ccol = ni * 16 + fr;           // 0..63
                        ushort hh, ll;
                        split2(acc[pass * 4 + mi][ni][j] + bv, hh, ll);
                        const int ccs = (ccol >> 2) ^ (rrow & 15);
                        kt[rrow * 64 + ccs * 4 + (ccol & 3)] = ((unsigned)ll << 16) | hh;
                    }
                }
            }
            f32x4 acc2[4][2] = {};
            float xdv4[4];
            #pragma unroll
            for (int tf = 0; tf < 4; ++tf) {
                const int rrow = tf * 16 + fr;
                const unsigned* rowp = &kt[rrow * 64];
                uint4 c0 = *reinterpret_cast<const uint4*>(&rowp[(((fk << 1))     ^ fr) << 2]);
                uint4 c1 = *reinterpret_cast<const uint4*>(&rowp[(((fk << 1) | 1) ^ fr) << 2]);
                uint4 c2 = *reinterpret_cast<const uint4*>(&rowp[(((fk << 1) + 8) ^ fr) << 2]);
                uint4 c3 = *reinterpret_cast<const uint4*>(&rowp[(((fk << 1) + 9) ^ fr) << 2]);
                unsigned u[16] = {c0.x,c0.y,c0.z,c0.w, c1.x,c1.y,c1.z,c1.w,
                                  c2.x,c2.y,c2.z,c2.w, c3.x,c3.y,c3.z,c3.w};
                bf16x8 Ah2[2], Al2[2];
                float xs = 0.f;
                #pragma unroll
                for (int e = 0; e < 16; ++e) {
                    const ushort hh = (ushort)(u[e] & 0xffffu);
                    const ushort ll = (ushort)(u[e] >> 16);
                    Ah2[e >> 3][e & 7] = (short)hh;
                    Al2[e >> 3][e & 7] = (short)ll;
                    const float kv = bf16_to_f32(hh) + bf16_to_f32(ll);
                    xs = fmaf(kv, kv, xs);
                }
                xs += __shfl_xor(xs, 16);
                xs += __shfl_xor(xs, 32);
                xdv4[tf] = 0.5f * xs;
                #pragma unroll
                for (int kc = 0; kc < 2; ++kc)
                    #pragma unroll
                    for (int mf = 0; mf < 2; ++mf) {
                        acc2[tf][mf] = __builtin_amdgcn_mfma_f32_16x16x32_bf16(Ah2[kc], Wh2[mf][kc], acc2[tf][mf], 0, 0, 0);
                        acc2[tf][mf] = __builtin_amdgcn_mfma_f32_16x16x32_bf16(Ah2[kc], Wl2[mf][kc], acc2[tf][mf], 0, 0, 0);
                        acc2[tf][mf] = __builtin_amdgcn_mfma_f32_16x16x32_bf16(Al2[kc], Wh2[mf][kc], acc2[tf][mf], 0, 0, 0);
                    }
            }
            float sm0 = 0.f, sm1 = 0.f;
            #pragma unroll
            for (int tf = 0; tf < 4; ++tf) {
                #pragma unroll
                for (int j = 0; j < 4; ++j) {
                    const int rloc = fk * 4 + j;
                    const float xdv = __shfl(xdv4[tf], (lane & 48) | rloc);
                    const int tg = trow0 + pass * 64 + tf * 16 + rloc;
                    float e0 = __expf(acc2[tf][0][j] - xdv) * rsm;
                    float e1 = __expf(acc2[tf][1][j] - xdv) * rsm;
                    phi[((size_t)bh * cN + tg) * cM + fr]      = f32_to_bf16_rne(e0);
                    phi[((size_t)bh * cN + tg) * cM + 16 + fr] = f32_to_bf16_rne(e1);
                    sm0 += e0; sm1 += e1;
                }
            }
            if (is_k) {
                sm0 += __shfl_xor(sm0, 16); sm0 += __shfl_xor(sm0, 32);
                sm1 += __shfl_xor(sm1, 16); sm1 += __shfl_xor(sm1, 32);
                const int tblk = (trow0 + pass * 64) >> 6;
                if (lane < 16) {
                    kpsum_p[((size_t)bh * 64 + tblk) * cM + lane]      = sm0;
                    kpsum_p[((size_t)bh * 64 + tblk) * cM + 16 + lane] = sm1;
                }
            }
        }
        return;
    }

    // FUSE=0 epilogue: 16x16 C layout col=lane&15, row=(lane>>4)*4+j
    #pragma unroll
    for (int ni = 0; ni < 4; ++ni) {
        const int c = col0 + wn * 64 + ni * 16 + fr;
        const float bv = bias[c];
        #pragma unroll
        for (int mi = 0; mi < 8; ++mi) {
            const int r0 = row0 + wm * 128 + mi * 16 + fk * 4;
            #pragma unroll
            for (int j = 0; j < 4; ++j) {
                const float val = acc[mi][ni][j] + bv;
                const int row = r0 + j;
                if (mode == 0) {
                    Cf[(size_t)row * Ndim + c] = val;
                } else {
                    const int b = row >> 12, tt = row & 4095;
                    const int h = c >> 6, d = c & 63;
                    Cb[(((size_t)(b * cH + h) * cN + tt) << 6) + d] = f32_to_bf16_rne(val);
                }
            }
        }
    }
}

// y = (qp . kptv) / (qp . kpsum + eps) via one MFMA pass (D appended as B-row 64)
// 4 waves/block; writes yh only (proj is TERMS=1)
__global__ __launch_bounds__(256)
void pv_mfma(const ushort* __restrict__ qp, const ushort* __restrict__ kptvx,
             ushort* __restrict__ yh)
{
    const int bh = blockIdx.x;
    const int wave = threadIdx.x >> 6, lane = threadIdx.x & 63;
    const int tblk = blockIdx.y * 4 + wave;
    const int b = bh / cH, h = bh % cH;
    const int t0 = tblk * 64;
    const int fr = lane & 15, fk = lane >> 4;
    bf16x8 Bf[5];
    #pragma unroll
    for (int nf = 0; nf < 5; ++nf)
        Bf[nf] = *reinterpret_cast<const bf16x8*>(&kptvx[(size_t)bh * 2560 + (nf * 16 + fr) * 32 + fk * 8]);
    f32x4 acc[4][5] = {};
    #pragma unroll
    for (int tf = 0; tf < 4; ++tf) {
        bf16x8 Af = *reinterpret_cast<const bf16x8*>(&qp[((size_t)bh * cN + t0 + tf * 16 + fr) * cM + fk * 8]);
        #pragma unroll
        for (int nf = 0; nf < 5; ++nf)
            acc[tf][nf] = __builtin_amdgcn_mfma_f32_16x16x32_bf16(Af, Bf[nf], acc[tf][nf], 0, 0, 0);
    }
    #pragma unroll
    for (int tf = 0; tf < 4; ++tf) {
        #pragma unroll
        for (int j = 0; j < 4; ++j) {
            const int rloc = fk * 4 + j;
            const int t = t0 + tf * 16 + rloc;
            const float Dv = __shfl(acc[tf][4][j], lane & 48) + 1e-8f;
            const float rD = 1.0f / Dv;
            #pragma unroll
            for (int nf = 0; nf < 4; ++nf) {
                float yv = acc[tf][nf][j] * rD;
                size_t oa = (size_t)(b * cN + t) * cC + h * 64 + nf * 16 + fr;
                yh[oa] = f32_to_bf16_rne(yv);
            }
        }
    }
}

// kptv partials: kptv_p[c][bh][d][m] over 32-t slices; c = chunk*2+half, 16 total
__global__ __launch_bounds__(256, 4)
void kptv_part(const ushort* __restrict__ vbf, const ushort* __restrict__ kp,
               float* __restrict__ kptv_p)
{
    const int bh = blockIdx.x, chunk = blockIdx.y;
    __shared__ float vl[64][68];
    __shared__ float kl[64][36];
    const int tid = threadIdx.x;
    const int half = tid >> 7;
    const int dg = (tid >> 3) & 15;
    const int mg = tid & 7;
    float acc[4][4] = {};
    for (int tile = 0; tile < 8; ++tile) {
        const int tb = chunk * 512 + tile * 64;
        #pragma unroll
        for (int i = 0; i < 2; ++i) {
            int idx = i * 256 + tid;
            int row = idx >> 3, seg = idx & 7;
            bf16x8 vv = *reinterpret_cast<const bf16x8*>(&vbf[((size_t)bh * cN + tb + row) * 64 + seg * 8]);
            float4 lo4 = make_float4(bf16_to_f32((ushort)vv[0]), bf16_to_f32((ushort)vv[1]),
                                     bf16_to_f32((ushort)vv[2]), bf16_to_f32((ushort)vv[3]));
            float4 hi4 = make_float4(bf16_to_f32((ushort)vv[4]), bf16_to_f32((ushort)vv[5]),
                                     bf16_to_f32((ushort)vv[6]), bf16_to_f32((ushort)vv[7]));
            *reinterpret_cast<float4*>(&vl[row][seg * 8])     = lo4;
            *reinterpret_cast<float4*>(&vl[row][seg * 8 + 4]) = hi4;
        }
        {
            int row = tid >> 2, seg = tid & 3;
            bf16x8 vv = *reinterpret_cast<const bf16x8*>(&kp[((size_t)bh * cN + tb + row) * 32 + seg * 8]);
            float4 lo4 = make_float4(bf16_to_f32((ushort)vv[0]), bf16_to_f32((ushort)vv[1]),
                                     bf16_to_f32((ushort)vv[2]), bf16_to_f32((ushort)vv[3]));
            float4 hi4 = make_float4(bf16_to_f32((ushort)vv[4]), bf16_to_f32((ushort)vv[5]),
                                     bf16_to_f32((ushort)vv[6]), bf16_to_f32((ushort)vv[7]));
            *reinterpret_cast<float4*>(&kl[row][seg * 8])     = lo4;
            *reinterpret_cast<float4*>(&kl[row][seg * 8 + 4]) = hi4;
        }
        __syncthreads();
        for (int t = 0; t < 32; ++t) {
            const int tt = half * 32 + t;
            float4 av = *reinterpret_cast<const float4*>(&vl[tt][dg * 4]);
            float4 bv = *reinterpret_cast<const float4*>(&kl[tt][mg * 4]);
            float a4[4] = {av.x, av.y, av.z, av.w};
            float b4[4] = {bv.x, bv.y, bv.z, bv.w};
            #pragma unroll
            for (int i = 0; i < 4; ++i)
                #pragma unroll
                for (int j = 0; j < 4; ++j)
                    acc[i][j] = fmaf(a4[i], b4[j], acc[i][j]);
        }
        __syncthreads();
    }
    float* outp = &kptv_p[(((size_t)chunk * 2 + half) * 96 + bh) * 2048];
    #pragma unroll
    for (int i = 0; i < 4; ++i)
        *reinterpret_cast<float4*>(&outp[(dg * 4 + i) * 32 + mg * 4]) =
            make_float4(acc[i][0], acc[i][1], acc[i][2], acc[i][3]);
}

// reduce partials -> kptvx bf16 [bh][80][32]: rows 0..63 kptv, row 64 kpsum, 65..79 zero
__global__ __launch_bounds__(256)
void kptv_reduce(const float* __restrict__ kptv_p, const float* __restrict__ kpsum_p,
                 ushort* __restrict__ kptvx)
{
    const int bh = blockIdx.x, tid = threadIdx.x;
    for (int l = tid; l < 2048; l += 256) {
        float s = 0.f;
        #pragma unroll
        for (int c = 0; c < 16; ++c) s += kptv_p[((size_t)c * 96 + bh) * 2048 + l];
        kptvx[(size_t)bh * 2560 + l] = f32_to_bf16_rne(s);
    }
    if (tid < 32) {
        float s = 0.f;
        #pragma unroll
        for (int c = 0; c < 64; ++c) s += kpsum_p[((size_t)bh * 64 + c) * cM + tid];
        kptvx[(size_t)bh * 2560 + 64 * 32 + tid] = f32_to_bf16_rne(s);
    }
    for (int l = tid; l < 480; l += 256)
        kptvx[(size_t)bh * 2560 + 65 * 32 + l] = 0;
}

extern "C" void kernel_launch(void* const* d_in, const int* in_sizes, int n_in,
                              void* d_out, int out_size, void* d_ws, size_t ws_size,
                              hipStream_t stream)
{
    const float* x      = (const float*)d_in[0];
    const float* kqv_w  = (const float*)d_in[1];
    const float* kqv_b  = (const float*)d_in[2];
    const float* proj_w = (const float*)d_in[3];
    const float* proj_b = (const float*)d_in[4];
    const float* w      = (const float*)d_in[5];

    char* wsb = (char*)d_ws;
    ushort* xh   = (ushort*)(wsb);                 // x hi plane, 50,331,648 B
    ushort* xl   = (ushort*)(wsb + 50331648);      // x lo plane
    ushort* yh   = (ushort*)(wsb + 100663296);     // y hi plane (written by pv)
    ushort* vbf  = (ushort*)(wsb + 201326592);     // [96][4096][64] bf16
    ushort* wh   = (ushort*)(wsb + 251658240);     // kqv_w hi
    ushort* wl_  = (ushort*)(wsb + 255197184);     // kqv_w lo
    ushort* pwh  = (ushort*)(wsb + 258736128);     // proj_w hi
    ushort* pwl  = (ushort*)(wsb + 259915776);     // proj_w lo (unused, layout keep)
    ushort* whb  = (ushort*)(wsb + 261095424);     // w hi (bf16)
    ushort* wlb  = (ushort*)(wsb + 261144576);     // w lo

    char* ob = (char*)d_out;
    ushort* kp      = (ushort*)ob;                 // [96][4096][32] bf16
    ushort* qp      = (ushort*)(ob + 25165824);    // [96][4096][32] bf16
    float*  kptv_p  = (float*)(ob + 50331648);     // [16][96][2048] fp32
    float*  kpsum_p = (float*)(ob + 62914560);     // [96][64][32] fp32
    ushort* kptvx   = (ushort*)(ob + 63700992);    // [96][80][32] bf16
    float*  out     = (float*)d_out;

    dim3 blk(256);
    // splits (RNE hi/lo planes)
    split_bf16<<<2048, blk, 0, stream>>>(x, xh, xl, 25165824 / 4);
    split_bf16<<<1728, blk, 0, stream>>>(kqv_w, wh, wl_, 1769472 / 4);
    split_bf16<<<576, blk, 0, stream>>>(proj_w, pwh, pwl, 589824 / 4);
    split_bf16<<<24, blk, 0, stream>>>(w, whb, wlb, 24576 / 4);
    // fused kq GEMM + feature map, TERMS=2 ((xh+xl)*wh; dropped x*wl ~ 5.7e-4
    // in kq, below kp's own bf16 rounding): kp, qp bf16 + kpsum partials
    gemm256<2, 1><<<dim3(6, 128), dim3(512), 0, stream>>>(
        xh, xl, wh, nullptr, kqv_b, nullptr, nullptr, 1536, 768, 0,
        kp, qp, kpsum_p, whb, wlb);
    // v = x @ kqv_w[1536:2304]^T  (bf16 out, 1-term, [b,h,t,d] layout)
    gemm256<1, 0><<<dim3(3, 128), dim3(512), 0, stream>>>(
        xh, nullptr, wh + (size_t)1536 * 768, nullptr, kqv_b + 1536,
        nullptr, vbf, 768, 768, 2, nullptr, nullptr, nullptr, nullptr, nullptr);
    // kptv partials + reduce
    kptv_part<<<dim3(96, 8), blk, 0, stream>>>(vbf, kp, kptv_p);
    kptv_reduce<<<dim3(96), blk, 0, stream>>>(kptv_p, kpsum_p, kptvx);
    // normalized PV -> yh (4 waves/block)
    pv_mfma<<<dim3(96, 16), blk, 0, stream>>>(qp, kptvx, yh);
    // out = y @ proj_w^T + proj_b  (1-term yh*pwh)
    gemm256<1, 0><<<dim3(3, 128), dim3(512), 0, stream>>>(
        yh, nullptr, pwh, nullptr, proj_b, out, nullptr, 768, 768, 0,
        nullptr, nullptr, nullptr, nullptr, nullptr);
}